// Round 2
// baseline (4537.788 us; speedup 1.0000x reference)
//
#include <hip/hip_runtime.h>
#include <math.h>

#define N_NODES 30000
#define N_EDGES 480000
#define N_GRAPHS 16
#define HID 128
#define HEADS 8
#define HEAD_DIM 16
#define NODE_IN 64
#define EDGE_IN 32
#define COND 8
#define NODE_OUT 64
#define NLAYERS 4
#define EF (N_EDGES + N_NODES) /* 510000 */
#define LN_EPS 1e-5f

__device__ __forceinline__ float gelu_f(float x) {
    return 0.5f * x * (1.0f + erff(x * 0.70710678118654752440f));
}

__device__ __forceinline__ void atomicMaxF(float* addr, float val) {
    if (val >= 0.0f) {
        atomicMax((int*)addr, __float_as_int(val));
    } else {
        atomicMin((unsigned int*)addr, __float_as_uint(val));
    }
}

// ---------- generic zero ----------
__global__ void zero_kernel(float* __restrict__ p, long n) {
    long i = (long)blockIdx.x * blockDim.x + threadIdx.x;
    long stride = (long)gridDim.x * blockDim.x;
    for (; i < n; i += stride) p[i] = 0.0f;
}

// ---------- time MLP: t[16] -> t_emb[16,128] ----------
__global__ void time_mlp_kernel(const float* __restrict__ t,
                                const float* __restrict__ tW1, const float* __restrict__ tb1,
                                const float* __restrict__ tW2, const float* __restrict__ tb2,
                                float* __restrict__ t_emb) {
    __shared__ float hsh[HID];
    int b = blockIdx.x, j = threadIdx.x;
    float tv = t[b];
    hsh[j] = gelu_f(tv * tW1[j] + tb1[j]);
    __syncthreads();
    float acc = tb2[j];
    for (int k = 0; k < HID; ++k) acc += hsh[k] * tW2[k * HID + j];
    t_emb[b * HID + j] = acc;
}

// ---------- concat x(64) + conditions[batch](8) -> xc[N,72] ----------
__global__ void concat_kernel(const float* __restrict__ x, const float* __restrict__ cond,
                              const int* __restrict__ batch, float* __restrict__ xc) {
    int idx = blockIdx.x * blockDim.x + threadIdx.x;
    if (idx >= N_NODES * 72) return;
    int n = idx / 72, c = idx % 72;
    xc[idx] = (c < NODE_IN) ? x[n * NODE_IN + c] : cond[batch[n] * COND + (c - NODE_IN)];
}

// ---------- generic GEMM: C[M,NCOL] = A[M,K] @ B[K,NCOL] + bias ----------
template <int NCOL, int R>
__global__ void gemm_kernel(const float* __restrict__ A, const float* __restrict__ B,
                            const float* __restrict__ bias, float* __restrict__ C,
                            int M, int K) {
    __shared__ float sh[R * HID];
    int j = threadIdx.x;
    int row0 = blockIdx.x * R;
    int total = R * K;
    for (int i = j; i < total; i += NCOL) {
        int r = i / K, k = i - r * K;
        int row = row0 + r;
        sh[r * K + k] = (row < M) ? A[(long)row * K + k] : 0.0f;
    }
    __syncthreads();
    float acc[R];
    float bv = bias ? bias[j] : 0.0f;
#pragma unroll
    for (int r = 0; r < R; ++r) acc[r] = bv;
    for (int k = 0; k < K; ++k) {
        float w = B[k * NCOL + j];
#pragma unroll
        for (int r = 0; r < R; ++r) acc[r] += sh[r * K + k] * w;
    }
#pragma unroll
    for (int r = 0; r < R; ++r) {
        int row = row0 + r;
        if (row < M) C[(long)row * NCOL + j] = acc[r];
    }
}

// ---------- in-place LayerNorm + GELU (+ optional t_emb[batch[row]]) ----------
__global__ void ln_gelu_kernel(float* __restrict__ X, const float* __restrict__ g,
                               const float* __restrict__ bta,
                               const float* __restrict__ t_emb, const int* __restrict__ batch) {
    int row = blockIdx.x, j = threadIdx.x;
    __shared__ float red[HID];
    float v = X[(long)row * HID + j];
    red[j] = v;
    __syncthreads();
    for (int s = 64; s > 0; s >>= 1) { if (j < s) red[j] += red[j + s]; __syncthreads(); }
    float mean = red[0] * (1.0f / HID);
    __syncthreads();
    float d = v - mean;
    red[j] = d * d;
    __syncthreads();
    for (int s = 64; s > 0; s >>= 1) { if (j < s) red[j] += red[j + s]; __syncthreads(); }
    float var = red[0] * (1.0f / HID);
    float y = gelu_f(d * rsqrtf(var + LN_EPS) * g[j] + bta[j]);
    if (t_emb) y += t_emb[batch[row] * HID + j];
    X[(long)row * HID + j] = y;
}

// ---------- fused edge-encode (for R edges) helper used by two kernels ----------
// Computes ea row = gelu(LN(edge_attr[e] @ eW + eb)) for real edges.
// Self-loop rows (e >= N_EDGES) take loop_attr (already final) when allowed.

// ---------- fused: edge-encode + segment-sum into loop_sum/cnt ----------
template <int R>
__global__ void edge_enc_loop_kernel(const float* __restrict__ edge_attr,
                                     const float* __restrict__ eW, const float* __restrict__ eb,
                                     const float* __restrict__ eg, const float* __restrict__ ebe,
                                     const int* __restrict__ ei_dst,
                                     float* __restrict__ loop_sum, float* __restrict__ cnt) {
    __shared__ float red[R * HID];
    __shared__ float sattr[R * EDGE_IN];
    __shared__ int sdst[R];
    int j = threadIdx.x;
    long e0 = (long)blockIdx.x * R;
    for (int i = j; i < R * EDGE_IN; i += HID) {
        int r = i >> 5, k = i & 31;
        long e = e0 + r;
        if (e < N_EDGES) sattr[i] = edge_attr[e * EDGE_IN + k];
    }
    if (j < R) {
        long e = e0 + j;
        if (e < N_EDGES) sdst[j] = ei_dst[e];
    }
    __syncthreads();
    float val[R];
#pragma unroll
    for (int r = 0; r < R; ++r) {
        float v = eb[j];
        for (int k = 0; k < EDGE_IN; ++k) v += sattr[r * EDGE_IN + k] * eW[k * HID + j];
        val[r] = v;
        red[r * HID + j] = v;
    }
    __syncthreads();
    for (int s = 64; s > 0; s >>= 1) {
        if (j < s) {
#pragma unroll
            for (int r = 0; r < R; ++r) red[r * HID + j] += red[r * HID + j + s];
        }
        __syncthreads();
    }
    float mean[R];
#pragma unroll
    for (int r = 0; r < R; ++r) mean[r] = red[r * HID] * (1.0f / HID);
    __syncthreads();
#pragma unroll
    for (int r = 0; r < R; ++r) { float d = val[r] - mean[r]; red[r * HID + j] = d * d; }
    __syncthreads();
    for (int s = 64; s > 0; s >>= 1) {
        if (j < s) {
#pragma unroll
            for (int r = 0; r < R; ++r) red[r * HID + j] += red[r * HID + j + s];
        }
        __syncthreads();
    }
#pragma unroll
    for (int r = 0; r < R; ++r) {
        long e = e0 + r;
        if (e >= N_EDGES) break;
        float var = red[r * HID] * (1.0f / HID);
        float y = gelu_f((val[r] - mean[r]) * rsqrtf(var + LN_EPS) * eg[j] + ebe[j]);
        int d = sdst[r];
        atomicAdd(&loop_sum[(long)d * HID + j], y);
        if (j == 0) atomicAdd(&cnt[d], 1.0f);
    }
}

__global__ void loop_div_kernel(float* __restrict__ loop_attr, const float* __restrict__ cnt) {
    int idx = blockIdx.x * blockDim.x + threadIdx.x;
    if (idx >= N_NODES * HID) return;
    int n = idx >> 7;
    loop_attr[idx] = loop_attr[idx] / fmaxf(cnt[n], 1.0f);
}

// ---------- init mx=-inf, den=0 ----------
__global__ void init_mx_den_kernel(float* __restrict__ mx, float* __restrict__ den) {
    int idx = blockIdx.x * blockDim.x + threadIdx.x;
    if (idx >= N_NODES * HEADS) return;
    mx[idx] = -INFINITY;
    den[idx] = 0.0f;
}

// ---------- fused: edge-encode recompute + em-GEMM + leakyrelu + logit + atomicMax ----------
template <int R>
__global__ void att_logit_kernel(const float* __restrict__ edge_attr,
                                 const float* __restrict__ eW, const float* __restrict__ eb,
                                 const float* __restrict__ eg, const float* __restrict__ ebe,
                                 const float* __restrict__ loop_attr,
                                 const float* __restrict__ cWe_l,  /* [128,128] */
                                 const float* __restrict__ catt_l, /* [128] */
                                 const float* __restrict__ xl, const float* __restrict__ xr,
                                 const int* __restrict__ ei_src, const int* __restrict__ ei_dst,
                                 float* __restrict__ logit, float* __restrict__ mx) {
    __shared__ float sh[R * HID];
    __shared__ float red[R * HID];
    __shared__ float sattr[R * EDGE_IN];
    __shared__ int ssrc[R], sdst[R];
    int j = threadIdx.x;
    long e0 = (long)blockIdx.x * R;
    for (int i = j; i < R * EDGE_IN; i += HID) {
        int r = i >> 5, k = i & 31;
        long e = e0 + r;
        if (e < N_EDGES) sattr[i] = edge_attr[e * EDGE_IN + k];
    }
    if (j < R) {
        long e = e0 + j;
        if (e < EF) {
            if (e < N_EDGES) { ssrc[j] = ei_src[e]; sdst[j] = ei_dst[e]; }
            else             { ssrc[j] = sdst[j] = (int)(e - N_EDGES); }
        }
    }
    __syncthreads();
    // recompute ea rows (real edges) / fetch loop_attr (self-loops)
    float val[R];
#pragma unroll
    for (int r = 0; r < R; ++r) {
        long e = e0 + r;
        float v = 0.0f;
        if (e < N_EDGES) {
            v = eb[j];
            for (int k = 0; k < EDGE_IN; ++k) v += sattr[r * EDGE_IN + k] * eW[k * HID + j];
        } else if (e < EF) {
            v = loop_attr[(long)(e - N_EDGES) * HID + j];
        }
        val[r] = v;
        red[r * HID + j] = v;
    }
    __syncthreads();
    for (int s = 64; s > 0; s >>= 1) {
        if (j < s) {
#pragma unroll
            for (int r = 0; r < R; ++r) red[r * HID + j] += red[r * HID + j + s];
        }
        __syncthreads();
    }
    float mean[R];
#pragma unroll
    for (int r = 0; r < R; ++r) mean[r] = red[r * HID] * (1.0f / HID);
    __syncthreads();
#pragma unroll
    for (int r = 0; r < R; ++r) { float d = val[r] - mean[r]; red[r * HID + j] = d * d; }
    __syncthreads();
    for (int s = 64; s > 0; s >>= 1) {
        if (j < s) {
#pragma unroll
            for (int r = 0; r < R; ++r) red[r * HID + j] += red[r * HID + j + s];
        }
        __syncthreads();
    }
#pragma unroll
    for (int r = 0; r < R; ++r) {
        long e = e0 + r;
        float out = val[r];  // self-loop rows: loop_attr already final
        if (e < N_EDGES) {
            float var = red[r * HID] * (1.0f / HID);
            out = gelu_f((val[r] - mean[r]) * rsqrtf(var + LN_EPS) * eg[j] + ebe[j]);
        }
        sh[r * HID + j] = out;
    }
    __syncthreads();
    // em GEMM: acc[r] = (ea_row @ cWe)[j]
    float acc[R];
#pragma unroll
    for (int r = 0; r < R; ++r) acc[r] = 0.0f;
    for (int k = 0; k < HID; ++k) {
        float w = cWe_l[k * HID + j];
#pragma unroll
        for (int r = 0; r < R; ++r) acc[r] += sh[r * HID + k] * w;
    }
    float cj = catt_l[j];
    int head = j >> 4;
    for (int r = 0; r < R; ++r) {
        long e = e0 + r;
        if (e >= EF) break;
        int s = ssrc[r], d = sdst[r];
        float m = xl[(long)s * HID + j] + xr[(long)d * HID + j] + acc[r];
        m = (m > 0.0f) ? m : 0.2f * m;
        float p = m * cj;
        p += __shfl_down(p, 8, 16);
        p += __shfl_down(p, 4, 16);
        p += __shfl_down(p, 2, 16);
        p += __shfl_down(p, 1, 16);
        if ((j & 15) == 0) {
            logit[e * HEADS + head] = p;
            atomicMaxF(&mx[(long)d * HEADS + head], p);
        }
    }
}

// ---------- exp(logit-mx), accumulate denominator ----------
__global__ void softmax_norm_kernel(const int* __restrict__ ei_dst, const float* __restrict__ mx,
                                    float* __restrict__ logit, float* __restrict__ den) {
    long idx = (long)blockIdx.x * blockDim.x + threadIdx.x;
    if (idx >= (long)EF * HEADS) return;
    long e = idx >> 3;
    int hh = (int)(idx & 7);
    int d = (e < N_EDGES) ? ei_dst[e] : (int)(e - N_EDGES);
    float ex = expf(logit[idx] - mx[(long)d * HEADS + hh]);
    logit[idx] = ex;
    atomicAdd(&den[(long)d * HEADS + hh], ex);
}

// ---------- alpha-weighted aggregation ----------
__global__ void aggregate_kernel(const float* __restrict__ logit, const float* __restrict__ den,
                                 const float* __restrict__ xl,
                                 const int* __restrict__ ei_src, const int* __restrict__ ei_dst,
                                 float* __restrict__ aggout) {
    long idx = (long)blockIdx.x * blockDim.x + threadIdx.x;
    if (idx >= (long)EF * HID) return;
    long e = idx >> 7;
    int j = (int)(idx & 127);
    int s, d;
    if (e < N_EDGES) { s = ei_src[e]; d = ei_dst[e]; }
    else             { s = d = (int)(e - N_EDGES); }
    int head = j >> 4;
    float alpha = logit[e * HEADS + head] / (den[(long)d * HEADS + head] + 1e-16f);
    atomicAdd(&aggout[(long)d * HID + j], alpha * xl[(long)s * HID + j]);
}

// ---------- h = gelu(aggout + cbias) + h ----------
__global__ void residual_kernel(const float* __restrict__ aggout, const float* __restrict__ cbias_l,
                                float* __restrict__ h) {
    int idx = blockIdx.x * blockDim.x + threadIdx.x;
    if (idx >= N_NODES * HID) return;
    int j = idx & 127;
    h[idx] = gelu_f(aggout[idx] + cbias_l[j]) + h[idx];
}

// ---------- pooling ----------
#define POOL_NODES 64
__global__ void pool_kernel(const float* __restrict__ h, const int* __restrict__ batch,
                            float* __restrict__ gsum, float* __restrict__ gcnt) {
    __shared__ float acc[N_GRAPHS][HID];
    __shared__ float cnt_sh[N_GRAPHS];
    int j = threadIdx.x;
    for (int g = 0; g < N_GRAPHS; ++g) acc[g][j] = 0.0f;
    if (j < N_GRAPHS) cnt_sh[j] = 0.0f;
    __syncthreads();
    int n0 = blockIdx.x * POOL_NODES;
    for (int i = 0; i < POOL_NODES; ++i) {
        int n = n0 + i;
        if (n >= N_NODES) break;
        int g = batch[n];
        acc[g][j] += h[(long)n * HID + j];
        if (j == 0) cnt_sh[g] += 1.0f;
    }
    __syncthreads();
    for (int g = 0; g < N_GRAPHS; ++g) atomicAdd(&gsum[g * HID + j], acc[g][j]);
    if (j < N_GRAPHS) atomicAdd(&gcnt[j], cnt_sh[j]);
}

// ---------- props head ----------
__global__ void props_kernel(const float* __restrict__ gsum, const float* __restrict__ gcnt,
                             const float* __restrict__ pW1, const float* __restrict__ pb1,
                             const float* __restrict__ pg, const float* __restrict__ pbe,
                             const float* __restrict__ pW2, const float* __restrict__ pb2,
                             float* __restrict__ out_props) {
    int g = blockIdx.x, j = threadIdx.x;
    __shared__ float feat[HID], red[HID], t2[HID];
    float c = fmaxf(gcnt[g], 1.0f);
    feat[j] = gsum[g * HID + j] / c;
    __syncthreads();
    float acc = pb1[j];
    for (int k = 0; k < HID; ++k) acc += feat[k] * pW1[k * HID + j];
    red[j] = acc;
    __syncthreads();
    for (int s = 64; s > 0; s >>= 1) { if (j < s) red[j] += red[j + s]; __syncthreads(); }
    float mean = red[0] * (1.0f / HID);
    __syncthreads();
    float dd = acc - mean;
    red[j] = dd * dd;
    __syncthreads();
    for (int s = 64; s > 0; s >>= 1) { if (j < s) red[j] += red[j + s]; __syncthreads(); }
    float var = red[0] * (1.0f / HID);
    t2[j] = gelu_f(dd * rsqrtf(var + LN_EPS) * pg[j] + pbe[j]);
    __syncthreads();
    if (j < COND) {
        float a = pb2[j];
        for (int k = 0; k < HID; ++k) a += t2[k] * pW2[k * COND + j];
        out_props[g * COND + j] = a;
    }
}

extern "C" void kernel_launch(void* const* d_in, const int* in_sizes, int n_in,
                              void* d_out, int out_size, void* d_ws, size_t ws_size,
                              hipStream_t stream) {
    const float* x        = (const float*)d_in[0];
    const float* edge_attr= (const float*)d_in[1];
    const float* t        = (const float*)d_in[2];
    const float* conds    = (const float*)d_in[3];
    const float* tW1      = (const float*)d_in[4];
    const float* tb1      = (const float*)d_in[5];
    const float* tW2      = (const float*)d_in[6];
    const float* tb2      = (const float*)d_in[7];
    const float* encW     = (const float*)d_in[8];
    const float* encb     = (const float*)d_in[9];
    const float* encg     = (const float*)d_in[10];
    const float* encbe    = (const float*)d_in[11];
    const float* eW       = (const float*)d_in[12];
    const float* eb       = (const float*)d_in[13];
    const float* eg       = (const float*)d_in[14];
    const float* ebe      = (const float*)d_in[15];
    const float* cWl      = (const float*)d_in[16];
    const float* cbl      = (const float*)d_in[17];
    const float* cWr      = (const float*)d_in[18];
    const float* cbr      = (const float*)d_in[19];
    const float* cWe      = (const float*)d_in[20];
    const float* catt     = (const float*)d_in[21];
    const float* cbias    = (const float*)d_in[22];
    const float* nW1      = (const float*)d_in[23];
    const float* nb1      = (const float*)d_in[24];
    const float* ng       = (const float*)d_in[25];
    const float* nbe      = (const float*)d_in[26];
    const float* nW2      = (const float*)d_in[27];
    const float* nb2      = (const float*)d_in[28];
    const float* pW1      = (const float*)d_in[29];
    const float* pb1      = (const float*)d_in[30];
    const float* pg       = (const float*)d_in[31];
    const float* pbe      = (const float*)d_in[32];
    const float* pW2      = (const float*)d_in[33];
    const float* pb2      = (const float*)d_in[34];
    const int* edge_index = (const int*)d_in[35];
    const int* batch      = (const int*)d_in[36];
    const int* ei_src = edge_index;
    const int* ei_dst = edge_index + N_EDGES;

    // workspace layout (~94 MB of f32)
    float* ws = (float*)d_ws;
    size_t off = 0;
    auto alloc = [&](size_t n) { float* p = ws + off; off += n; return p; };
    float* t_emb     = alloc((size_t)N_GRAPHS * HID);
    float* h         = alloc((size_t)N_NODES * HID);
    float* loop_attr = alloc((size_t)N_NODES * HID);
    float* cnt       = alloc((size_t)N_NODES);
    float* xl        = alloc((size_t)N_NODES * HID);
    float* xr        = alloc((size_t)N_NODES * HID);
    float* logit     = alloc((size_t)EF * HEADS);      // 4.08M floats
    float* mx        = alloc((size_t)N_NODES * HEADS);
    float* den       = alloc((size_t)N_NODES * HEADS);
    float* aggout    = alloc((size_t)N_NODES * HID);
    float* gsum      = alloc((size_t)N_GRAPHS * HID);
    float* gcnt      = alloc((size_t)N_GRAPHS);
    // aliases (disjoint lifetimes):
    float* xc   = logit;  // [N,72] = 2.16M floats, used only pre-layers; logit is 4.08M
    float* tmp1 = xl;     // used only post-layers
    (void)ws_size; (void)in_sizes; (void)n_in; (void)out_size;

    float* pred_noise = (float*)d_out;                              // [N,64]
    float* pred_props = (float*)d_out + (size_t)N_NODES * NODE_OUT; // [16,8]

    // 1. time MLP
    hipLaunchKernelGGL(time_mlp_kernel, dim3(N_GRAPHS), dim3(HID), 0, stream,
                       t, tW1, tb1, tW2, tb2, t_emb);
    // 2. concat
    hipLaunchKernelGGL(concat_kernel, dim3((N_NODES * 72 + 255) / 256), dim3(256), 0, stream,
                       x, conds, batch, xc);
    // 3. node encoder gemm + LN/GELU (+t_emb[batch])
    hipLaunchKernelGGL((gemm_kernel<HID, 8>), dim3(N_NODES / 8), dim3(HID), 0, stream,
                       xc, encW, encb, h, N_NODES, 72);
    hipLaunchKernelGGL(ln_gelu_kernel, dim3(N_NODES), dim3(HID), 0, stream,
                       h, encg, encbe, t_emb, batch);
    // 4. self-loop attr = segment-mean of encoded edge_attr over dst (encode fused)
    hipLaunchKernelGGL(zero_kernel, dim3(1024), dim3(256), 0, stream,
                       loop_attr, (long)N_NODES * HID);
    hipLaunchKernelGGL(zero_kernel, dim3(64), dim3(256), 0, stream, cnt, (long)N_NODES);
    hipLaunchKernelGGL((edge_enc_loop_kernel<8>), dim3(N_EDGES / 8), dim3(HID), 0, stream,
                       edge_attr, eW, eb, eg, ebe, ei_dst, loop_attr, cnt);
    hipLaunchKernelGGL(loop_div_kernel, dim3((N_NODES * HID + 255) / 256), dim3(256), 0, stream,
                       loop_attr, cnt);

    // 5. layers
    for (int l = 0; l < NLAYERS; ++l) {
        const float* cWl_l = cWl + (size_t)l * HID * HID;
        const float* cWr_l = cWr + (size_t)l * HID * HID;
        const float* cWe_l = cWe + (size_t)l * HID * HID;
        const float* cbl_l = cbl + (size_t)l * HID;
        const float* cbr_l = cbr + (size_t)l * HID;
        const float* catt_l = catt + (size_t)l * HID;
        const float* cbias_l = cbias + (size_t)l * HID;

        hipLaunchKernelGGL((gemm_kernel<HID, 8>), dim3(N_NODES / 8), dim3(HID), 0, stream,
                           h, cWl_l, cbl_l, xl, N_NODES, HID);
        hipLaunchKernelGGL((gemm_kernel<HID, 8>), dim3(N_NODES / 8), dim3(HID), 0, stream,
                           h, cWr_l, cbr_l, xr, N_NODES, HID);
        hipLaunchKernelGGL(init_mx_den_kernel, dim3((N_NODES * HEADS + 255) / 256), dim3(256), 0,
                           stream, mx, den);
        hipLaunchKernelGGL((att_logit_kernel<8>), dim3(EF / 8), dim3(HID), 0, stream,
                           edge_attr, eW, eb, eg, ebe, loop_attr,
                           cWe_l, catt_l, xl, xr, ei_src, ei_dst, logit, mx);
        hipLaunchKernelGGL(softmax_norm_kernel,
                           dim3((int)(((long)EF * HEADS + 255) / 256)), dim3(256), 0, stream,
                           ei_dst, mx, logit, den);
        hipLaunchKernelGGL(zero_kernel, dim3(1024), dim3(256), 0, stream,
                           aggout, (long)N_NODES * HID);
        hipLaunchKernelGGL(aggregate_kernel,
                           dim3((int)(((long)EF * HID + 255) / 256)), dim3(256), 0, stream,
                           logit, den, xl, ei_src, ei_dst, aggout);
        hipLaunchKernelGGL(residual_kernel, dim3((N_NODES * HID + 255) / 256), dim3(256), 0, stream,
                           aggout, cbias_l, h);
    }

    // 6. noise head
    hipLaunchKernelGGL((gemm_kernel<HID, 8>), dim3(N_NODES / 8), dim3(HID), 0, stream,
                       h, nW1, nb1, tmp1, N_NODES, HID);
    hipLaunchKernelGGL(ln_gelu_kernel, dim3(N_NODES), dim3(HID), 0, stream,
                       tmp1, ng, nbe, (const float*)nullptr, (const int*)nullptr);
    hipLaunchKernelGGL((gemm_kernel<NODE_OUT, 8>), dim3(N_NODES / 8), dim3(NODE_OUT), 0, stream,
                       tmp1, nW2, nb2, pred_noise, N_NODES, HID);

    // 7. pooling + props head
    hipLaunchKernelGGL(zero_kernel, dim3(4), dim3(256), 0, stream,
                       gsum, (long)N_GRAPHS * HID);
    hipLaunchKernelGGL(zero_kernel, dim3(1), dim3(64), 0, stream, gcnt, (long)N_GRAPHS);
    hipLaunchKernelGGL(pool_kernel, dim3((N_NODES + POOL_NODES - 1) / POOL_NODES), dim3(HID), 0,
                       stream, h, batch, gsum, gcnt);
    hipLaunchKernelGGL(props_kernel, dim3(N_GRAPHS), dim3(HID), 0, stream,
                       gsum, gcnt, pW1, pb1, pg, pbe, pW2, pb2, pred_props);
}